// Round 9
// baseline (1739.749 us; speedup 1.0000x reference)
//
#include <hip/hip_runtime.h>
#include <math.h>

#define KB       4            // logical ranks doing the work
#define NBOOT    32           // launched blocks (>= 4 guaranteed on one XCD)
#define NTHREADS 256
#define NW       4            // waves per block
#define HID      4096
#define HB       (HID / KB)   // 1024 neurons per rank
#define NPT      4            // neurons per thread
#define TT       1000
#define PP       16
#define SLOTW    32           // u64 stride per slot line (256B, line-aligned)

#define BETA 0.9f
#define THRV 0.5f
#define DTV  0.005f

// DPP cross-lane: quad_perm {1,0,3,2}=0xB1 (lane^1), {2,3,0,1}=0x4E (lane^2),
// row_ror:8 = 0x128 (lane^8 within row-of-16). All VALU-pipe (no DS).
template<int CTRL>
__device__ __forceinline__ float dppx(float v) {
    return __int_as_float(__builtin_amdgcn_update_dpp(
        0, __float_as_int(v), CTRL, 0xF, 0xF, true));
}

__device__ __forceinline__ unsigned long long AL(const unsigned long long* p) {
    return __hip_atomic_load(p, __ATOMIC_RELAXED, __HIP_MEMORY_SCOPE_AGENT);
}
__device__ __forceinline__ void AS(unsigned long long* p, unsigned long long v) {
    __hip_atomic_store(p, v, __ATOMIC_RELAXED, __HIP_MEMORY_SCOPE_AGENT);
}
// sc0 = L1-bypass; store lands in the local XCD's (write-back) L2; a load from a
// CU on the SAME XCD hits that L2. Cross-XCD it is never visible (probe exploits this).
__device__ __forceinline__ void st64_sc0(unsigned long long* p, unsigned long long v) {
    asm volatile("global_store_dwordx2 %0, %1, off sc0" :: "v"(p), "v"(v) : "memory");
}
__device__ __forceinline__ unsigned long long ld64_sc0(const unsigned long long* p) {
    unsigned long long v;
    asm volatile("global_load_dwordx2 %0, %1, off sc0\n\ts_waitcnt vmcnt(0)"
                 : "=v"(v) : "v"(p) : "memory");
    return v;
}
__device__ __forceinline__ void ld64x3_sc0(const unsigned long long* p0,
                                           const unsigned long long* p1,
                                           const unsigned long long* p2,
                                           unsigned long long& v0,
                                           unsigned long long& v1,
                                           unsigned long long& v2) {
    asm volatile("global_load_dwordx2 %0, %3, off sc0\n\t"
                 "global_load_dwordx2 %1, %4, off sc0\n\t"
                 "global_load_dwordx2 %2, %5, off sc0\n\t"
                 "s_waitcnt vmcnt(0)"
                 : "=&v"(v0), "=&v"(v1), "=&v"(v2)
                 : "v"(p0), "v"(p1), "v"(p2) : "memory");
}
__device__ __forceinline__ unsigned long long memrealtime() {
    unsigned long long t;
    asm volatile("s_memrealtime %0\n\ts_waitcnt lgkmcnt(0)" : "=s"(t));
    return t;
}

// zero probe/alive/masks each call (before snn_kernel, stream-ordered).
__global__ void zero_kernel(unsigned long long* probe, unsigned* alive,
                            unsigned long long* masks) {
    int i = threadIdx.x;
    for (int k = i; k < NBOOT * SLOTW; k += 256) probe[k] = 0ull;
    if (i < NBOOT) { alive[i] = 0u; masks[i] = 0ull; }
}

__global__ __launch_bounds__(NTHREADS, 1)
void snn_kernel(const float* __restrict__ x,
                const float* __restrict__ noise,
                const float* __restrict__ Win,
                const float* __restrict__ Wout,
                const float* __restrict__ pin,
                const float* __restrict__ pout,
                const float* __restrict__ lvec,
                const float* __restrict__ stdv,
                float* __restrict__ out,
                unsigned long long* __restrict__ slotsL2,
                unsigned long long* __restrict__ slotsAG,
                unsigned long long* __restrict__ probe,
                unsigned* __restrict__ alive,
                unsigned long long* __restrict__ masks)
{
    const int bid  = blockIdx.x;
    const int tid  = threadIdx.x;
    const int wave = tid >> 6;
    const int lane = tid & 63;

    __shared__ float part[NW][20];       // per-wave butterfly results
    __shared__ float ubuf[NW][16];       // per-wave u broadcast area
    __shared__ unsigned mlds[NBOOT];     // gathered visibility masks

    // ======== bootstrap: empirical L2-affinity probe -> pick 4 co-XCD blocks ========
    if (tid == 0)
        __hip_atomic_store(&alive[bid], 1u, __ATOMIC_RELAXED, __HIP_MEMORY_SCOPE_AGENT);
    if (wave == 0) {
        // rendezvous: wait until all blocks are running (bounds probe-window skew)
        if (lane < NBOOT) {
            unsigned a; int sp = 0;
            do {
                a = __hip_atomic_load(&alive[lane], __ATOMIC_RELAXED,
                                      __HIP_MEMORY_SCOPE_AGENT);
            } while (!a && ++sp < (1 << 22));
        }
        // probe window (~5us): keep sc0-storing my line; sc0-read everyone's line.
        const unsigned long long MG = 0xC0DE5EED00000000ull;
        unsigned seen = 0;
        unsigned long long t0 = memrealtime();
        do {
            if (lane == 0) st64_sc0(&probe[(size_t)bid * SLOTW], MG | (unsigned)bid);
            unsigned long long v = ld64_sc0(&probe[(size_t)(lane & 31) * SLOTW]);
            unsigned long long bal =
                __ballot(v == (MG | (unsigned)(lane & 31)));
            seen |= (unsigned)(bal | (bal >> 32));
        } while (memrealtime() - t0 < 500);
        if (lane == 0)
            AS(&masks[bid], 0xA11E000000000000ull | (unsigned long long)seen);
        // gather all masks (agent scope, tag-checked)
        if (lane < NBOOT) {
            unsigned long long mv; int sp = 0;
            do {
                mv = AL(&masks[lane]);
            } while (((mv >> 48) != 0xA11Eull) && ++sp < (1 << 22));
            mlds[lane] = (unsigned)mv;
        }
    }
    __syncthreads();

    // deterministic selection: first block with >=4 mutual-visibility peers leads
    int leader = -1; unsigned grp = 0;
    for (int i = 0; i < NBOOT && leader < 0; ++i) {
        unsigned mi = mlds[i], mut = 0;
        for (int j = 0; j < NBOOT; ++j)
            if (((mi >> j) & 1u) && ((mlds[j] >> i) & 1u)) mut |= (1u << j);
        if (__popc(mut) >= KB) { leader = i; grp = mut; }
    }
    int sc0_ok = 1;
    if (leader < 0) { grp = 0xFu; sc0_ok = 0; }   // fallback: first 4, agent path
    unsigned g = grp; int ids[4];
    #pragma unroll
    for (int k = 0; k < 4; ++k) { ids[k] = __builtin_ctz(g); g &= g - 1; }
    const bool chosen = (bid == ids[0]) | (bid == ids[1]) |
                        (bid == ids[2]) | (bid == ids[3]);
    if (!chosen) return;                 // block-uniform
    const int b = (bid == ids[0]) ? 0 : (bid == ids[1]) ? 1
                : (bid == ids[2]) ? 2 : 3;   // logical rank

    // ======== worker setup ========
    const int h0 = b * HB + tid * NPT;   // four consecutive neurons per thread

    const bool lb0 = (lane & 1) != 0;
    const bool lb1 = (lane & 2) != 0;
    const bool lb2 = (lane & 4) != 0;
    const bool lb3 = (lane & 8) != 0;

    // remote ranks in ascending order (for canonical sum tree)
    const int rbA = (b == 0) ? 1 : 0;
    const int rbB = (b <= 1) ? 2 : 1;
    const int rbC = (b <= 2) ? 3 : 2;

    float lv[PP];
    #pragma unroll
    for (int p = 0; p < PP; p += 4) {
        float4 t4 = *(const float4*)&lvec[p];
        lv[p] = t4.x; lv[p+1] = t4.y; lv[p+2] = t4.z; lv[p+3] = t4.w;
    }
    float pl[NPT][PP], po[NPT][PP];
    #pragma unroll
    for (int j = 0; j < NPT; ++j) {
        #pragma unroll
        for (int p = 0; p < PP; p += 4) {
            float4 a = *(const float4*)&pin[(h0+j)*PP + p];
            pl[j][p]   = a.x*lv[p];   pl[j][p+1] = a.y*lv[p+1];
            pl[j][p+2] = a.z*lv[p+2]; pl[j][p+3] = a.w*lv[p+3];
            float4 e4 = *(const float4*)&pout[(h0+j)*PP + p];
            po[j][p]   = e4.x; po[j][p+1] = e4.y;
            po[j][p+2] = e4.z; po[j][p+3] = e4.w;
        }
    }
    float win[NPT][6];
    #pragma unroll
    for (int j = 0; j < NPT; ++j) {
        const float2* wr = (const float2*)&Win[(h0+j)*6];
        float2 wA = wr[0], wB = wr[1], wC = wr[2];
        win[j][0]=wA.x; win[j][1]=wA.y; win[j][2]=wB.x;
        win[j][3]=wB.y; win[j][4]=wC.x; win[j][5]=wC.y;
    }
    float4 woa = *(const float4*)&Wout[h0];        // Wout[0][h0..h0+3]
    float4 wob = *(const float4*)&Wout[HID + h0];  // Wout[1][h0..h0+3]

    float4 sd4 = *(const float4*)&stdv[h0];
    float dd[NPT], sg[NPT];
    {
        float sdv[4] = { sd4.x, sd4.y, sd4.z, sd4.w };
        #pragma unroll
        for (int j = 0; j < NPT; ++j) {
            float sig = 1.f / (1.f + expf(-sdv[j]));
            float tau = sig * 0.03f + 0.02f;
            dd[j] = expf(-DTV / tau);
            sg[j] = DTV / (tau * 0.002f);
        }
    }
    const float DECAY_R = expf(-2.5f);

    float mem[NPT], rr[NPT], ss[NPT], pre[NPT];
    #pragma unroll
    for (int j = 0; j < NPT; ++j) { mem[j] = 0.f; rr[j] = 0.f; ss[j] = 0.f; }

    const float2* x2 = (const float2*)x;
    float4 nz = *(const float4*)&noise[h0];           // t = 0
    float2 xa = x2[0], xb = x2[1], xc = x2[2];

    float uu[16];
    #pragma unroll
    for (int p = 0; p < 16; ++p) uu[p] = 0.f;

    int use_sc0 = sc0_ok;   // per-wave sticky: drop to agent polling if L2 path dead

    for (int t = 0; t <= TT; ++t) {
        // prefetch next step's inputs (overlaps exchange below)
        float4 nz_n = nz; float2 xa_n = xa, xb_n = xb, xc_n = xc;
        if (t < TT - 1) {
            const int tn = t + 1;
            nz_n = *(const float4*)&noise[tn * HID + h0];
            xa_n = x2[tn*3]; xb_n = x2[tn*3+1]; xc_n = x2[tn*3+2];
        }

        float bs = 0.f;
        const int par = t & 1;
        if (t > 0) {
            // ---- pa: 18 per-thread partials from r_{t-1} (canonical tree) ----
            float pa[18];
            #pragma unroll
            for (int p = 0; p < PP; ++p)
                pa[p] = (po[0][p]*rr[0] + po[1][p]*rr[1])
                      + (po[2][p]*rr[2] + po[3][p]*rr[3]);
            pa[16] = (woa.x*rr[0] + woa.y*rr[1]) + (woa.z*rr[2] + woa.w*rr[3]);
            pa[17] = (wob.x*rr[0] + wob.y*rr[1]) + (wob.z*rr[2] + wob.w*rr[3]);

            // ---- reduce-scatter butterfly: lane ends with u[lane&15], y[lane&1] ----
            float a1[8], yv;
            #pragma unroll
            for (int k = 0; k < 8; ++k) {
                float keep = lb0 ? pa[2*k+1] : pa[2*k];
                float send = lb0 ? pa[2*k]   : pa[2*k+1];
                a1[k] = keep + dppx<0xB1>(send);          // xor1 (DPP)
            }
            {
                float keep = lb0 ? pa[17] : pa[16];
                float send = lb0 ? pa[16] : pa[17];
                yv = keep + dppx<0xB1>(send);
            }
            float a2[4];
            #pragma unroll
            for (int k = 0; k < 4; ++k) {
                float keep = lb1 ? a1[2*k+1] : a1[2*k];
                float send = lb1 ? a1[2*k]   : a1[2*k+1];
                a2[k] = keep + dppx<0x4E>(send);          // xor2 (DPP)
            }
            yv += dppx<0x4E>(yv);
            float a3[2];
            #pragma unroll
            for (int k = 0; k < 2; ++k) {
                float keep = lb2 ? a2[2*k+1] : a2[2*k];
                float send = lb2 ? a2[2*k]   : a2[2*k+1];
                a3[k] = keep + __shfl_xor(send, 4, 64);   // xor4 (DS)
            }
            yv += __shfl_xor(yv, 4, 64);
            float uv;
            {
                float keep = lb3 ? a3[1] : a3[0];
                float send = lb3 ? a3[0] : a3[1];
                uv = keep + dppx<0x128>(send);            // xor8 (DPP row_ror:8)
            }
            yv += dppx<0x128>(yv);
            uv += __shfl_xor(uv, 16, 64);                 // xor16 (DS)
            uv += __shfl_xor(uv, 32, 64);                 // xor32 (DS)
            yv += __shfl_xor(yv, 16, 64);
            yv += __shfl_xor(yv, 32, 64);

            // ---- per-wave partials to LDS ----
            if (lane < 18) part[wave][lane] = (lane < 16) ? uv : yv;
            __syncthreads();

            // ---- every wave: block sum (fixed tree, bit-identical) ----
            if (lane < 18) {
                bs = (part[0][lane] + part[1][lane])
                   + (part[2][lane] + part[3][lane]);
            }

            // ---- wave 0: publish tagged partials (dual scope) ----
            if (wave == 0 && lane < 18) {
                union { float f; unsigned u; } cv; cv.f = bs;
                unsigned long long pk = ((unsigned long long)(unsigned)t << 32)
                                      | (unsigned long long)cv.u;
                const size_t si = (size_t)(par*KB + b)*SLOTW + lane;
                st64_sc0(&slotsL2[si], pk);   // fast path: shared-XCD L2
                AS(&slotsAG[si], pk);         // hedge: far coherence point
            }
        }

        if (t < TT) {
            // ---- u-independent update pieces (overlap publish drain + poll) ----
            float nzv[4] = { nz.x, nz.y, nz.z, nz.w };
            #pragma unroll
            for (int j = 0; j < NPT; ++j) {
                float xw = win[j][0]*xa.x + win[j][1]*xa.y
                         + win[j][2]*xb.x + win[j][3]*xb.y
                         + win[j][4]*xc.x + win[j][5]*xc.y;
                float rst = (mem[j] - THRV > 0.f) ? THRV : 0.f;
                pre[j] = BETA*mem[j] + xw + nzv[j] / 10.0f - rst;
            }
        }

        if (t > 0 && (t < TT || b == 0)) {
            // ---- poll 3 remote ranks' tagged slots ----
            const size_t sb = (size_t)par * KB;
            float f0 = 0.f, f1 = 0.f, f2 = 0.f;
            unsigned long long va = 0, vb = 0, vc = 0;
            if (use_sc0) {
                int got = 1;
                if (lane < 18) {
                    const unsigned long long* pa_ = &slotsL2[(sb + rbA)*SLOTW + lane];
                    const unsigned long long* pb_ = &slotsL2[(sb + rbB)*SLOTW + lane];
                    const unsigned long long* pc_ = &slotsL2[(sb + rbC)*SLOTW + lane];
                    const int K = (t == 1) ? 4096 : 512;
                    int sp = 0, ok;
                    do {
                        ld64x3_sc0(pa_, pb_, pc_, va, vb, vc);
                        ok = ((unsigned)(va >> 32) == (unsigned)t)
                           & ((unsigned)(vb >> 32) == (unsigned)t)
                           & ((unsigned)(vc >> 32) == (unsigned)t);
                    } while (!ok && ++sp < K);
                    got = ok;
                }
                if (!__all(got)) use_sc0 = 0;   // wave-uniform sticky fallback
            }
            if (!use_sc0) {
                if (lane < 18) {
                    const unsigned long long* pa_ = &slotsAG[(sb + rbA)*SLOTW + lane];
                    const unsigned long long* pb_ = &slotsAG[(sb + rbB)*SLOTW + lane];
                    const unsigned long long* pc_ = &slotsAG[(sb + rbC)*SLOTW + lane];
                    int sp2 = 0;
                    do {
                        va = AL(pa_); vb = AL(pb_); vc = AL(pc_);
                    } while ((((unsigned)(va >> 32) != (unsigned)t) |
                              ((unsigned)(vb >> 32) != (unsigned)t) |
                              ((unsigned)(vc >> 32) != (unsigned)t)) &&
                             ++sp2 < (1 << 20));
                }
            }
            if (lane < 18) {
                union { unsigned u; float f; } c0, c1, c2;
                c0.u = (unsigned)va; c1.u = (unsigned)vb; c2.u = (unsigned)vc;
                f0 = c0.f; f1 = c1.f; f2 = c2.f;
            }
            // canonical rank-order tree: (R0+R1)+(R2+R3), identical everywhere
            float total = (b < 2) ? ((bs + f0) + (f1 + f2))
                                  : ((f0 + f1) + (f2 + bs));
            if (lane < 16) ubuf[wave][lane] = total;
            if (b == 0 && wave == 0 && lane >= 16 && lane < 18)
                out[(t-1)*2 + (lane - 16)] = total;   // y[t-1]

            float4 u0 = *(const float4*)&ubuf[wave][0];
            float4 u1 = *(const float4*)&ubuf[wave][4];
            float4 u2 = *(const float4*)&ubuf[wave][8];
            float4 u3 = *(const float4*)&ubuf[wave][12];
            uu[0]=u0.x; uu[1]=u0.y; uu[2]=u0.z; uu[3]=u0.w;
            uu[4]=u1.x; uu[5]=u1.y; uu[6]=u1.z; uu[7]=u1.w;
            uu[8]=u2.x; uu[9]=u2.y; uu[10]=u2.z; uu[11]=u2.w;
            uu[12]=u3.x; uu[13]=u3.y; uu[14]=u3.z; uu[15]=u3.w;
        }

        if (t < TT) {
            // ---- finish update: mem = pre + rec, spike, traces ----
            #pragma unroll
            for (int j = 0; j < NPT; ++j) {
                float ra = pl[j][0]*uu[0];
                float rb2_ = pl[j][8]*uu[8];
                #pragma unroll
                for (int p = 1; p < 8; ++p) {
                    ra   += pl[j][p]*uu[p];
                    rb2_ += pl[j][p+8]*uu[p+8];
                }
                float rec = ra + rb2_;
                mem[j] = pre[j] + rec;
                float spk = (mem[j] - THRV > 0.f) ? 1.f : 0.f;
                ss[j] = ss[j]*DECAY_R + sg[j]*spk;
                rr[j] = dd[j]*rr[j] + DTV*ss[j];
            }
            nz = nz_n; xa = xa_n; xb = xb_n; xc = xc_n;
        }
    }
}

extern "C" void kernel_launch(void* const* d_in, const int* in_sizes, int n_in,
                              void* d_out, int out_size, void* d_ws, size_t ws_size,
                              hipStream_t stream)
{
    const float* x     = (const float*)d_in[0];
    const float* noise = (const float*)d_in[1];
    const float* Win   = (const float*)d_in[2];
    const float* Wout  = (const float*)d_in[3];
    const float* pin   = (const float*)d_in[4];
    const float* pout  = (const float*)d_in[5];
    const float* l     = (const float*)d_in[6];
    const float* stdv  = (const float*)d_in[7];
    float* out = (float*)d_out;
    unsigned long long* slotsL2 = (unsigned long long*)d_ws;                  // 2KB
    unsigned long long* slotsAG = (unsigned long long*)((char*)d_ws + 4096);  // 2KB
    unsigned long long* probe   = (unsigned long long*)((char*)d_ws + 8192);  // 8KB
    unsigned*           alive   = (unsigned*)((char*)d_ws + 16384);           // 128B
    unsigned long long* masks   = (unsigned long long*)((char*)d_ws + 16640); // 256B

    hipLaunchKernelGGL(zero_kernel, dim3(1), dim3(256), 0, stream,
                       probe, alive, masks);
    hipLaunchKernelGGL(snn_kernel, dim3(NBOOT), dim3(NTHREADS), 0, stream,
                       x, noise, Win, Wout, pin, pout, l, stdv,
                       out, slotsL2, slotsAG, probe, alive, masks);
}